// Round 12
// baseline (49.950 us; speedup 1.0000x reference)
//
#include <hip/hip_runtime.h>
#include <hip/hip_bf16.h>

// LS2T iterated sums (ORDER=3): B=64, T=4096, D=128, F=64, C=6.
// m_c(t,f) = seq[b,t,:]·kernel[c,:,f] + bias[c,f]
// Y1 = sum m0; Y2 = sum m2*cumx(m1); Y3 = sum m5*cumx(m4*cumx(m3))
//
// Round 12: 4-wave/256-thr blocks, ONE cg per block (cg = blockIdx.x&1) ->
// 1024 blocks = exactly 4 blocks/CU, 4 independent small barrier domains.
// Both cg recurrences unified into one 6-register linear form (no divergence):
//   x5+=r*x3; x4+=r*x1; x3+=q*x0; x2+=r; x1+=q; x0+=p
// with (p,q,r) = (m0,m1,m2) [cg0: a0=x0,s1=x1,s2=x2,q2=x4] or (m3,m4,m5)
// [cg1: su..qwvu = x0..x5]. Depth-2 two-set register prefetch, ring-4 LDS
// (16 KB), verified zero-conflict swizzle, no-drain barriers, trunc v_perm
// pack. Register budget ~110 unified -> 4 waves/SIMD guaranteed.

#define B_ 64
#define T_ 4096
#define D_ 128
#define F_ 64
#define TB 512             // t per block
#define TGROUPS (T_ / TB)  // 8
#define CHT 16             // t per chunk
#define NITER (TB / CHT)   // 32
#define TPB 256
#define RING 4

typedef __attribute__((ext_vector_type(8))) short short8v;
typedef __attribute__((ext_vector_type(4))) float f32x4;

__device__ __forceinline__ unsigned short bfb(float x) {
    __hip_bfloat16 h = __float2bfloat16(x);   // RNE (B operand only)
    unsigned short u;
    __builtin_memcpy(&u, &h, 2);
    return u;
}

// barrier WITHOUT vmcnt drain: waits only LDS ops, keeps global loads in flight
#define BAR() asm volatile("s_waitcnt lgkmcnt(0)\n\ts_barrier" ::: "memory")

__global__ __launch_bounds__(TPB)
void ls2t_kernel(const float* __restrict__ seq,
                 const float* __restrict__ kern,
                 const float* __restrict__ bias,
                 float* __restrict__ ws)
{
    __shared__ unsigned short slds[RING][CHT * D_];   // 4 x 4 KB bf16

    const int tid  = threadIdx.x;
    const int tg   = blockIdx.x >> 1;
    const int cg   = blockIdx.x & 1;   // 0 -> c0..2 (Y1,Y2), 1 -> c3..5 (Y3)
    const int b    = blockIdx.y;
    const int lane = tid & 63;
    const int wv   = tid >> 6;         // f-wave 0..3
    const int fr   = lane & 15;
    const int lg   = lane >> 4;
    const int f    = wv * 16 + fr;

    // ---- B fragments in registers (mfma B: col=lane&15=f, k=(lane>>4)*8+j)
    short8v bfrag[3][4];
    float bc[3];
    #pragma unroll
    for (int cc = 0; cc < 3; ++cc) {
        const int c = cg * 3 + cc;
        bc[cc] = bias[c * F_ + f];
        #pragma unroll
        for (int ks = 0; ks < 4; ++ks) {
            const float* kp = kern + ((size_t)c * D_ + ks * 32 + lg * 8) * F_ + f;
            short8v bf;
            #pragma unroll
            for (int j = 0; j < 8; ++j) bf[j] = (short)bfb(kp[(size_t)j * F_]);
            bfrag[cc][ks] = bf;
        }
    }

    const float* sbase = seq + ((size_t)b * T_ + (size_t)tg * TB) * D_;

    // staging (verified R6 map, 2 units/thread): unit u = k*TPB+tid ->
    // row sr = u>>5 (0..15), float4-index c4 = u&31. Chunk row r holds
    // t_local = (r>>2)*128 + i*4 + (r&3) (lane-group lg owns contiguous
    // t-stripe [lg*128,+128) over the 32 chunks). LDS 16B unit jb of row r
    // stores global d-block (jb ^ (r&7)).
    const float* gp[2];
    int woff[2];
    #pragma unroll
    for (int k = 0; k < 2; ++k) {
        const int u  = k * TPB + tid;
        const int sr = u >> 5, c4 = u & 31;
        gp[k]   = sbase + ((size_t)((sr >> 2) * 128 + (sr & 3))) * D_ + c4 * 4;
        woff[k] = sr * D_ + 8 * ((c4 >> 1) ^ (sr & 7)) + 4 * (c4 & 1);
    }

    struct VSet { float4 a, b; };
    VSet vA, vB;
    auto issue = [&](int i, VSet& vs) {
        vs.a = *reinterpret_cast<const float4*>(gp[0] + (size_t)i * 4 * D_);
        vs.b = *reinterpret_cast<const float4*>(gp[1] + (size_t)i * 4 * D_);
    };
    auto wst = [&](int bufi, const VSet& vs) {
        unsigned short* L = &slds[bufi][0];
        uint2 pa, pb;
        pa.x = __builtin_amdgcn_perm(__float_as_uint(vs.a.y),
                                     __float_as_uint(vs.a.x), 0x07060302u);
        pa.y = __builtin_amdgcn_perm(__float_as_uint(vs.a.w),
                                     __float_as_uint(vs.a.z), 0x07060302u);
        pb.x = __builtin_amdgcn_perm(__float_as_uint(vs.b.y),
                                     __float_as_uint(vs.b.x), 0x07060302u);
        pb.y = __builtin_amdgcn_perm(__float_as_uint(vs.b.w),
                                     __float_as_uint(vs.b.z), 0x07060302u);
        *reinterpret_cast<uint2*>(&L[woff[0]]) = pa;
        *reinterpret_cast<uint2*>(&L[woff[1]]) = pb;
    };

    // unified scan state (cg0: a0=x0,s1=x1,s2=x2,q2=x4; cg1: su..qwvu=x0..x5)
    float x0 = 0.f, x1 = 0.f, x2 = 0.f, x3 = 0.f, x4 = 0.f, x5 = 0.f;

    auto compute = [&](int bufi) {
        f32x4 acc[3];
        #pragma unroll
        for (int cc = 0; cc < 3; ++cc)
            acc[cc] = (f32x4){bc[cc], bc[cc], bc[cc], bc[cc]};

        #pragma unroll
        for (int ks = 0; ks < 4; ++ks) {
            short8v a = *reinterpret_cast<const short8v*>(
                &slds[bufi][fr * D_ + 8 * ((ks * 4 + lg) ^ (fr & 7))]);
            #pragma unroll
            for (int cc = 0; cc < 3; ++cc)
                acc[cc] = __builtin_amdgcn_mfma_f32_16x16x32_bf16(
                    a, bfrag[cc][ks], acc[cc], 0, 0, 0);
        }

        // lane owns t = tg*512 + lg*128 + i*4 + r  -> chain in-lane
        #pragma unroll
        for (int r = 0; r < 4; ++r) {
            float p = acc[0][r], q = acc[1][r], rr = acc[2][r];
            x5 = fmaf(rr, x3, x5);   // qwvu += m5*qvu            (cg1)
            x4 = fmaf(rr, x1, x4);   // q2 += m2*s1 / qwv += m5*sv
            x3 = fmaf(q,  x0, x3);   // qvu += m4*su              (cg1)
            x2 += rr;                // s2 / sw
            x1 += q;                 // s1 / sv
            x0 += p;                 // a0 / su
        }
    };

    // ---- pipeline: depth-2 two-set prefetch, ring-4 LDS, 1 barrier/chunk ----
    issue(0, vA);
    issue(1, vB);
    wst(0, vA);
    issue(2, vA);
    BAR();

    #pragma unroll 1
    for (int g = 0; g < 28; g += 4) {
        wst(1, vB); issue(g + 3, vB); BAR(); compute(0);
        wst(2, vA); issue(g + 4, vA); BAR(); compute(1);
        wst(3, vB); issue(g + 5, vB); BAR(); compute(2);
        wst(0, vA); issue(g + 6, vA); BAR(); compute(3);
    }
    // epilogue: chunks 28..31
    wst(1, vB); issue(31, vB); BAR(); compute(0);   // compute 28
    wst(2, vA);                BAR(); compute(1);   // compute 29
    wst(3, vB);                BAR(); compute(2);   // compute 30
    compute(3);                                     // compute 31

    // ---- merge the 4 lane-group stripes (time order: lg ascending) ----
    #pragma unroll
    for (int m = 16; m <= 32; m <<= 1) {
        float o0 = __shfl_xor(x0, m), o1 = __shfl_xor(x1, m);
        float o2 = __shfl_xor(x2, m), o3 = __shfl_xor(x3, m);
        float o4 = __shfl_xor(x4, m), o5 = __shfl_xor(x5, m);
        const bool up = (lane & m) != 0;   // this lane holds the LATER segment
        float A0 = up ? o0 : x0, B0 = up ? x0 : o0;
        float A1 = up ? o1 : x1, B1 = up ? x1 : o1;
        float A2 = up ? o2 : x2, B2 = up ? x2 : o2;
        float A3 = up ? o3 : x3, B3 = up ? x3 : o3;
        float A4 = up ? o4 : x4, B4 = up ? x4 : o4;
        float A5 = up ? o5 : x5, B5 = up ? x5 : o5;
        x5 = A5 + B5 + A3 * B2 + A0 * B4;
        x4 = A4 + B4 + A1 * B2;
        x3 = A3 + B3 + A0 * B1;
        x2 = A2 + B2;
        x1 = A1 + B1;
        x0 = A0 + B0;
    }

    if (lg == 0) {
        float* wp = ws + (((size_t)b * TGROUPS + tg) * F_ + f) * 10;
        if (cg == 0) {
            wp[0] = x0; wp[1] = x1; wp[2] = x2; wp[3] = x4;
        } else {
            wp[4] = x0; wp[5] = x1; wp[6] = x2;
            wp[7] = x3; wp[8] = x4; wp[9] = x5;
        }
    }
}

struct St { float a0, s1, s2, q2, su, sv, sw, qvu, qwv, qwvu; };

__device__ __forceinline__ St mergeSt(const St& A, const St& B) {
    St r;
    r.a0   = A.a0 + B.a0;
    r.q2   = A.q2 + B.q2 + A.s1 * B.s2;
    r.s1   = A.s1 + B.s1;
    r.s2   = A.s2 + B.s2;
    r.qwvu = A.qwvu + B.qwvu + A.qvu * B.sw + A.su * B.qwv;
    r.qwv  = A.qwv + B.qwv + A.sv * B.sw;
    r.qvu  = A.qvu + B.qvu + A.su * B.sv;
    r.su   = A.su + B.su;
    r.sv   = A.sv + B.sv;
    r.sw   = A.sw + B.sw;
    return r;
}

__global__ __launch_bounds__(64)
void ls2t_fold_kernel(const float* __restrict__ ws, float* __restrict__ out)
{
    const int b = blockIdx.x;
    const int f = threadIdx.x;
    St A = {0, 0, 0, 0, 0, 0, 0, 0, 0, 0};
    #pragma unroll
    for (int g = 0; g < TGROUPS; ++g) {
        const float* rp = ws + (((size_t)b * TGROUPS + g) * F_ + f) * 10;
        St r = {rp[0], rp[1], rp[2], rp[3], rp[4],
                rp[5], rp[6], rp[7], rp[8], rp[9]};
        A = mergeSt(A, r);
    }
    float* op = out + ((size_t)b * F_ + f) * 3;
    op[0] = A.a0;
    op[1] = A.q2;
    op[2] = A.qwvu;
}

extern "C" void kernel_launch(void* const* d_in, const int* in_sizes, int n_in,
                              void* d_out, int out_size, void* d_ws, size_t ws_size,
                              hipStream_t stream) {
    const float* seq  = (const float*)d_in[0];
    const float* kern = (const float*)d_in[1];
    const float* bias = (const float*)d_in[2];
    float* out = (float*)d_out;
    float* ws  = (float*)d_ws;   // B_*TGROUPS*F_*10*4 = 1.31 MB

    dim3 g1(TGROUPS * 2, B_);    // 1024 blocks x 256 thr -> 4 blocks/CU
    ls2t_kernel<<<g1, TPB, 0, stream>>>(seq, kern, bias, ws);
    ls2t_fold_kernel<<<B_, F_, 0, stream>>>(ws, out);
}

// Round 13
// 43.432 us; speedup vs baseline: 1.1501x; 1.1501x over previous
//
#include <hip/hip_runtime.h>
#include <hip/hip_bf16.h>

// LS2T iterated sums (ORDER=3): B=64, T=4096, D=128, F=64, C=6.
// m_c(t,f) = seq[b,t,:]·kernel[c,:,f] + bias[c,f]
// Y1 = sum m0; Y2 = sum m2*cumx(m1); Y3 = sum m5*cumx(m4*cumx(m3))
//
// Round 13: R6 structure + global_load_lds DMA staging (T3/T4). LDS holds
// f32 chunks (ring-4 x 8KB); each wave issues ONE global_load_lds_dwordx4
// per chunk (its 2 rows, 1KB, per-lane pre-swizzled source, linear dest).
// Counted vmcnt(2) -> barrier -> issue(i+3) -> compute(i): loads never
// drain, staging needs zero registers. Read side: 2 swizzled ds_read_b128
// (f32) + v_perm trunc-pack -> MFMA. cg-split waves, B-frags in AGPRs,
// unified 6-reg scan (R12, validated), one butterfly pair at the end.

#define B_ 64
#define T_ 4096
#define D_ 128
#define F_ 64
#define TB 512             // t per block
#define TGROUPS (T_ / TB)  // 8
#define CHT 16             // t per chunk
#define NITER (TB / CHT)   // 32
#define TPB 512
#define RING 4

typedef __attribute__((ext_vector_type(8))) short short8v;
typedef __attribute__((ext_vector_type(4))) float f32x4;

__device__ __forceinline__ unsigned short bfb(float x) {
    __hip_bfloat16 h = __float2bfloat16(x);   // RNE (B operand only)
    unsigned short u;
    __builtin_memcpy(&u, &h, 2);
    return u;
}

// barrier WITHOUT vmcnt drain: waits only LDS ops, keeps DMAs in flight
#define BAR() asm volatile("s_waitcnt lgkmcnt(0)\n\ts_barrier" ::: "memory")
#define VW(n) asm volatile("s_waitcnt vmcnt(" #n ")" ::: "memory")

__global__ __launch_bounds__(TPB)
void ls2t_kernel(const float* __restrict__ seq,
                 const float* __restrict__ kern,
                 const float* __restrict__ bias,
                 float* __restrict__ ws)
{
    __shared__ float slds[RING][CHT * D_];   // 4 x 8 KB f32

    const int tid  = threadIdx.x;
    const int tg   = blockIdx.x;
    const int b    = blockIdx.y;
    const int lane = tid & 63;
    const int w    = tid >> 6;
    const int cg   = w >> 2;       // 0 -> c0..2 (Y1,Y2), 1 -> c3..5 (Y3)
    const int wv   = w & 3;        // f-range of this wave
    const int fr   = lane & 15;
    const int lg   = lane >> 4;
    const int f    = wv * 16 + fr;

    // ---- B fragments in registers (mfma B: col=lane&15=f, k=(lane>>4)*8+j)
    short8v bfrag[3][4];
    float bc[3];
    #pragma unroll
    for (int cc = 0; cc < 3; ++cc) {
        const int c = cg * 3 + cc;
        bc[cc] = bias[c * F_ + f];
        #pragma unroll
        for (int ks = 0; ks < 4; ++ks) {
            const float* kp = kern + ((size_t)c * D_ + ks * 32 + lg * 8) * F_ + f;
            short8v bf;
            #pragma unroll
            for (int j = 0; j < 8; ++j) bf[j] = (short)bfb(kp[(size_t)j * F_]);
            bfrag[cc][ks] = bf;
        }
    }

    const float* sbase = seq + ((size_t)b * T_ + (size_t)tg * TB) * D_;

    // ---- DMA staging geometry ----
    // Wave w stages LDS rows {2w, 2w+1} of each chunk: one
    // global_load_lds_dwordx4 (64 lanes x 16B = 1KB), dest linear
    // (base + lane*16). Row r of chunk i holds t_local = (r>>2)*128+i*4+(r&3)
    // (lane-group lg owns contiguous t-stripe [lg*128,+128) over 32 chunks).
    // Swizzle (m173, pre-swizzled SOURCE): LDS 16B-unit u of row r contains
    // global unit (u&24) | ((u^r)&7).
    const int r_lane = 2 * w + (lane >> 5);   // LDS row this lane fills
    const int u_lane = lane & 31;             // dest 16B unit within row
    const int gu     = (u_lane & 24) | ((u_lane ^ r_lane) & 7);
    const float* gsrc0 = sbase
        + ((size_t)((r_lane >> 2) * 128 + (r_lane & 3))) * D_ + gu * 4;

    auto issue = [&](int i, int bufi) {
        const float* src = gsrc0 + (size_t)i * 4 * D_;
        void* dst = (void*)&slds[bufi][w * 256];   // 2 rows = 256 f32
        __builtin_amdgcn_global_load_lds(
            (const __attribute__((address_space(1))) void*)src,
            (__attribute__((address_space(3))) void*)dst, 16, 0, 0);
    };

    // unified scan state (cg0: a0=x0,s1=x1,s2=x2,q2=x4; cg1: su..qwvu=x0..x5)
    float x0 = 0.f, x1 = 0.f, x2 = 0.f, x3 = 0.f, x4 = 0.f, x5 = 0.f;

    auto compute = [&](int bufi) {
        const float* L = &slds[bufi][0];
        f32x4 acc[3];
        #pragma unroll
        for (int cc = 0; cc < 3; ++cc)
            acc[cc] = (f32x4){bc[cc], bc[cc], bc[cc], bc[cc]};

        #pragma unroll
        for (int ks = 0; ks < 4; ++ks) {
            // lane (fr,lg) reads A[row=fr][d = ks*32+lg*8 .. +8] (f32),
            // i.e. 16B-units u0, u0+1 with the store-side swizzle applied
            const int u0 = ks * 8 + lg * 2;
            const int s0 = (u0 & 24) | ((u0 ^ fr) & 7);
            const int s1 = ((u0 + 1) & 24) | (((u0 + 1) ^ fr) & 7);
            float4 fa = *reinterpret_cast<const float4*>(&L[fr * 128 + s0 * 4]);
            float4 fb = *reinterpret_cast<const float4*>(&L[fr * 128 + s1 * 4]);
            uint4 pk;
            pk.x = __builtin_amdgcn_perm(__float_as_uint(fa.y),
                                         __float_as_uint(fa.x), 0x07060302u);
            pk.y = __builtin_amdgcn_perm(__float_as_uint(fa.w),
                                         __float_as_uint(fa.z), 0x07060302u);
            pk.z = __builtin_amdgcn_perm(__float_as_uint(fb.y),
                                         __float_as_uint(fb.x), 0x07060302u);
            pk.w = __builtin_amdgcn_perm(__float_as_uint(fb.w),
                                         __float_as_uint(fb.z), 0x07060302u);
            short8v a = *reinterpret_cast<short8v*>(&pk);
            #pragma unroll
            for (int cc = 0; cc < 3; ++cc)
                acc[cc] = __builtin_amdgcn_mfma_f32_16x16x32_bf16(
                    a, bfrag[cc][ks], acc[cc], 0, 0, 0);
        }

        // lane owns t = tg*512 + lg*128 + i*4 + r  -> chain in-lane
        #pragma unroll
        for (int r = 0; r < 4; ++r) {
            float p = acc[0][r], q = acc[1][r], rr = acc[2][r];
            x5 = fmaf(rr, x3, x5);   // qwvu += m5*qvu            (cg1)
            x4 = fmaf(rr, x1, x4);   // q2 += m2*s1 / qwv += m5*sv
            x3 = fmaf(q,  x0, x3);   // qvu += m4*su              (cg1)
            x2 += rr;                // s2 / sw
            x1 += q;                 // s1 / sv
            x0 += p;                 // a0 / su
        }
    };

    // ---- pipeline: DMA 3 chunks ahead, counted vmcnt (never 0), ring-4 ----
    issue(0, 0); issue(1, 1); issue(2, 2);

    #pragma unroll 1
    for (int i = 0; i < NITER - 3; ++i) {
        VW(2);                 // own DMA for chunk i landed (2 newer in flight)
        BAR();                 // => all waves' chunk-i slices landed
        issue(i + 3, (i + 3) & 3);   // overwrites buf (i-1)%4: safe post-BAR
        compute(i & 3);
    }
    // tail: chunks 29,30,31 (outstanding DMAs drain 2 -> 0)
    VW(2); BAR(); compute(1);
    VW(1); BAR(); compute(2);
    VW(0); BAR(); compute(3);

    // ---- merge the 4 lane-group stripes (time order: lg ascending) ----
    #pragma unroll
    for (int m = 16; m <= 32; m <<= 1) {
        float o0 = __shfl_xor(x0, m), o1 = __shfl_xor(x1, m);
        float o2 = __shfl_xor(x2, m), o3 = __shfl_xor(x3, m);
        float o4 = __shfl_xor(x4, m), o5 = __shfl_xor(x5, m);
        const bool up = (lane & m) != 0;   // this lane holds the LATER segment
        float A0 = up ? o0 : x0, B0 = up ? x0 : o0;
        float A1 = up ? o1 : x1, B1 = up ? x1 : o1;
        float A2 = up ? o2 : x2, B2 = up ? x2 : o2;
        float A3 = up ? o3 : x3, B3 = up ? x3 : o3;
        float A4 = up ? o4 : x4, B4 = up ? x4 : o4;
        float A5 = up ? o5 : x5, B5 = up ? x5 : o5;
        x5 = A5 + B5 + A3 * B2 + A0 * B4;
        x4 = A4 + B4 + A1 * B2;
        x3 = A3 + B3 + A0 * B1;
        x2 = A2 + B2;
        x1 = A1 + B1;
        x0 = A0 + B0;
    }

    if (lg == 0) {
        float* wp = ws + (((size_t)b * TGROUPS + tg) * F_ + f) * 10;
        if (cg == 0) {
            wp[0] = x0; wp[1] = x1; wp[2] = x2; wp[3] = x4;
        } else {
            wp[4] = x0; wp[5] = x1; wp[6] = x2;
            wp[7] = x3; wp[8] = x4; wp[9] = x5;
        }
    }
}

struct St { float a0, s1, s2, q2, su, sv, sw, qvu, qwv, qwvu; };

__device__ __forceinline__ St mergeSt(const St& A, const St& B) {
    St r;
    r.a0   = A.a0 + B.a0;
    r.q2   = A.q2 + B.q2 + A.s1 * B.s2;
    r.s1   = A.s1 + B.s1;
    r.s2   = A.s2 + B.s2;
    r.qwvu = A.qwvu + B.qwvu + A.qvu * B.sw + A.su * B.qwv;
    r.qwv  = A.qwv + B.qwv + A.sv * B.sw;
    r.qvu  = A.qvu + B.qvu + A.su * B.sv;
    r.su   = A.su + B.su;
    r.sv   = A.sv + B.sv;
    r.sw   = A.sw + B.sw;
    return r;
}

__global__ __launch_bounds__(64)
void ls2t_fold_kernel(const float* __restrict__ ws, float* __restrict__ out)
{
    const int b = blockIdx.x;
    const int f = threadIdx.x;
    St A = {0, 0, 0, 0, 0, 0, 0, 0, 0, 0};
    #pragma unroll
    for (int g = 0; g < TGROUPS; ++g) {
        const float* rp = ws + (((size_t)b * TGROUPS + g) * F_ + f) * 10;
        St r = {rp[0], rp[1], rp[2], rp[3], rp[4],
                rp[5], rp[6], rp[7], rp[8], rp[9]};
        A = mergeSt(A, r);
    }
    float* op = out + ((size_t)b * F_ + f) * 3;
    op[0] = A.a0;
    op[1] = A.q2;
    op[2] = A.qwvu;
}

extern "C" void kernel_launch(void* const* d_in, const int* in_sizes, int n_in,
                              void* d_out, int out_size, void* d_ws, size_t ws_size,
                              hipStream_t stream) {
    const float* seq  = (const float*)d_in[0];
    const float* kern = (const float*)d_in[1];
    const float* bias = (const float*)d_in[2];
    float* out = (float*)d_out;
    float* ws  = (float*)d_ws;   // B_*TGROUPS*F_*10*4 = 1.31 MB

    dim3 g1(TGROUPS, B_);        // 512 blocks x 512 thr
    ls2t_kernel<<<g1, TPB, 0, stream>>>(seq, kern, bias, ws);
    ls2t_fold_kernel<<<B_, F_, 0, stream>>>(ws, out);
}